// Round 15
// baseline (909.902 us; speedup 1.0000x reference)
//
#include <hip/hip_runtime.h>

// AttentionRNN: B=64, NUM=8, TC=64, H=128. bn=512 sequences.
// R15: 512 thr/block (8 waves, 2/SIMD), 256 blocks, 2 seqs/block.
// All mappings from validated kernels, all known failure modes removed:
//  A: quarter in WAVE bits -> conflict-free ATTW reads (R10's 4.2e7 fix)
//  B: R1's 128-thread reduce. C/softmax/E: R5 pair-split (validated 3x).
//  D: R2's balanced 3-half-col map (all 8 waves) + R9's simple chunk stream
//     (no manual dbuf - R11 lesson). Register budget ~110 < 128 cap (R3 lesson).

#define OFF_ATTW  0        // [128][64]
#define OFF_U     8192     // [64][64]
#define OFF_XMRM  12288    // [mat(2)][seq(2)][384]
#define OFF_HST   13824    // [2][128]
#define OFF_HPP   14080    // [2][4][64]
#define OFF_HPART 14592    // [2][64]
#define OFF_XTV   14720    // [2][128]
#define OFF_VV    14976    // [64]
#define OFF_RED   15040    // [8]
#define LDS_FLOATS 15048   // ~58.8 KB

#define DOT8(ACC, W, V0, V1) \
    ACC += W[0]*V0.x + W[1]*V0.y + W[2]*V0.z + W[3]*V0.w \
         + W[4]*V1.x + W[5]*V1.y + W[6]*V1.z + W[7]*V1.w;

__global__ __launch_bounds__(512)
void attn_gru_kernel(const float* __restrict__ x, const float* __restrict__ att_v,
                     const float* __restrict__ att_w, const float* __restrict__ att_u,
                     const float* __restrict__ gk, const float* __restrict__ grk,
                     const float* __restrict__ gbias, float* __restrict__ out) {
    __shared__ float lds[LDS_FLOATS];
    const int tid = threadIdx.x;
    const int bn0 = blockIdx.x * 2;

    // ---- stage att_w, U, v; zero h
    for (int i = tid; i < 8192; i += 512) lds[OFF_ATTW + i] = att_w[i];
    for (int i = tid; i < 4096; i += 512) lds[OFF_U + i] = att_u[i];
    if (tid < 64)  lds[OFF_VV + tid] = att_v[tid];
    if (tid < 256) lds[OFF_HST + tid] = 0.0f;
    __syncthreads();

    // ---- thread mappings
    const int wv   = tid >> 6;            // wave id
    const int lane = tid & 63;
    // A: seq/quarter in wave bits (conflict-free)
    const int aseq = wv >> 2;
    const int aq   = wv & 3;
    // C (R5-validated): pair-split
    const int cseq = tid >> 8;
    const int chh  = (tid >> 1) & 127;
    const int csh  = tid & 1;
    // D (R2-validated): 3 half-cols/thread
    const int half = tid & 1;
    const int c0   = tid >> 1;            // 0..255
    const int col1 = c0 + 256;
    const int m1   = (col1 >= 384) ? 1 : 0;          // wave-uniform
    const int c1   = col1 - m1 * 384;
    const float* wb0 = gk  + (size_t)(half * 64) * 384 + c0;
    const float* wb1 = (m1 ? grk : gk) + (size_t)(half * 64) * 384 + c1;
    const float* wb2 = grk + (size_t)(half * 64) * 384 + (128 + c0);
    const float b0 = gbias[c0];
    const float b1 = gbias[m1 * 384 + c1];
    const float b2 = gbias[384 + 128 + c0];

    // ---- prologue: uproj half in registers (R5-validated)
    float up[32];
    #pragma unroll
    for (int k = 0; k < 32; ++k) up[k] = 0.0f;
    {
        const float* xb = x + (size_t)(bn0 + cseq) * 8192 + chh;
        for (int t = 0; t < 64; ++t) {
            float xvp = xb[t * 128];
            const float4* Ur = (const float4*)(lds + OFF_U + t * 64 + csh * 32);
            #pragma unroll
            for (int k4 = 0; k4 < 8; ++k4) {
                float4 u = Ur[k4];
                up[k4*4+0] += xvp * u.x; up[k4*4+1] += xvp * u.y;
                up[k4*4+2] += xvp * u.z; up[k4*4+3] += xvp * u.w;
            }
        }
    }
    float sv = 0.0f;
    #pragma unroll
    for (int k = 0; k < 32; ++k) sv += lds[OFF_VV + csh * 32 + k];

    const float* xcol = x + (size_t)(bn0 + cseq) * 8192 + chh;

    __syncthreads();

    #pragma unroll 1
    for (int t = 0; t < 64; ++t) {
        float xv = xcol[t * 128];

        // ---- A: h_part partials; ATTW rows wave-uniform, lanes consecutive
        {
            float pa = 0.0f;
            const float4* hb4 = (const float4*)(lds + OFF_HST + aseq * 128 + aq * 32);
            const float* wgl = lds + OFF_ATTW + (aq * 32) * 64 + lane;
            #pragma unroll
            for (int k4 = 0; k4 < 8; ++k4) {
                float4 hv = hb4[k4];
                pa += hv.x * wgl[(k4*4+0)*64] + hv.y * wgl[(k4*4+1)*64]
                    + hv.z * wgl[(k4*4+2)*64] + hv.w * wgl[(k4*4+3)*64];
            }
            lds[OFF_HPP + (aseq * 4 + aq) * 64 + lane] = pa;
        }
        __syncthreads();

        // ---- B: reduce quarters (R1-validated)
        if (tid < 128) {
            int sq = tid >> 6, ss = tid & 63;
            lds[OFF_HPART + sq * 64 + ss] =
                  lds[OFF_HPP + (sq * 4 + 0) * 64 + ss]
                + lds[OFF_HPP + (sq * 4 + 1) * 64 + ss]
                + lds[OFF_HPP + (sq * 4 + 2) * 64 + ss]
                + lds[OFF_HPP + (sq * 4 + 3) * 64 + ss];
        }
        __syncthreads();

        // ---- C: e = sum_s tanh(hp+up)*v; max-free softmax (R5-validated)
        float den = 0.0f;
        {
            const float4* hp4 = (const float4*)(lds + OFF_HPART + cseq * 64 + csh * 32);
            const float4* vv4 = (const float4*)(lds + OFF_VV + csh * 32);
            #pragma unroll
            for (int k4 = 0; k4 < 8; ++k4) {
                float4 hp = hp4[k4];
                float4 v4 = vv4[k4];
                den += v4.x * __fdividef(1.0f, __expf(2.0f * (hp.x + up[k4*4+0])) + 1.0f);
                den += v4.y * __fdividef(1.0f, __expf(2.0f * (hp.y + up[k4*4+1])) + 1.0f);
                den += v4.z * __fdividef(1.0f, __expf(2.0f * (hp.z + up[k4*4+2])) + 1.0f);
                den += v4.w * __fdividef(1.0f, __expf(2.0f * (hp.w + up[k4*4+3])) + 1.0f);
            }
        }
        float ep = sv - 2.0f * den;
        float e  = ep + __shfl_xor(ep, 1);
        float p  = __expf(e);               // |e| <= sum|v| ~ 5: fp32-safe
        float wsum = p;
        #pragma unroll
        for (int off = 1; off <= 32; off <<= 1) wsum += __shfl_xor(wsum, off);
        if (lane == 0) lds[OFF_RED + wv] = wsum;   // each hh counted twice
        __syncthreads();
        float denom = 0.5f * (lds[OFF_RED + cseq * 4 + 0] + lds[OFF_RED + cseq * 4 + 1]
                            + lds[OFF_RED + cseq * 4 + 2] + lds[OFF_RED + cseq * 4 + 3]);
        float av = __fdividef(p, denom);
        lds[OFF_XTV + cseq * 128 + chh] = av * xv;
        __syncthreads();

        // ---- D: 3 half-cols/thread, 8 chunks x 8 rows, simple load-then-FMA
        float a00 = 0.f, a01 = 0.f, a10 = 0.f, a11 = 0.f, a20 = 0.f, a21 = 0.f;
        #pragma unroll 1
        for (int c = 0; c < 8; ++c) {
            float w0[8], w1[8], w2[8];
            #pragma unroll
            for (int r = 0; r < 8; ++r) {
                w0[r] = wb0[(size_t)(c * 8 + r) * 384];
                w1[r] = wb1[(size_t)(c * 8 + r) * 384];
                w2[r] = wb2[(size_t)(c * 8 + r) * 384];
            }
            const int rb = half * 64 + c * 8;
            float4 xA0 = *(const float4*)(lds + OFF_XTV + rb);
            float4 xA1 = *(const float4*)(lds + OFF_XTV + rb + 4);
            float4 xB0 = *(const float4*)(lds + OFF_XTV + 128 + rb);
            float4 xB1 = *(const float4*)(lds + OFF_XTV + 128 + rb + 4);
            float4 hA0 = *(const float4*)(lds + OFF_HST + rb);
            float4 hA1 = *(const float4*)(lds + OFF_HST + rb + 4);
            float4 hB0 = *(const float4*)(lds + OFF_HST + 128 + rb);
            float4 hB1 = *(const float4*)(lds + OFF_HST + 128 + rb + 4);
            float4 sA0 = m1 ? hA0 : xA0;   // wave-uniform select
            float4 sA1 = m1 ? hA1 : xA1;
            float4 sB0 = m1 ? hB0 : xB0;
            float4 sB1 = m1 ? hB1 : xB1;
            DOT8(a00, w0, xA0, xA1); DOT8(a01, w0, xB0, xB1);
            DOT8(a10, w1, sA0, sA1); DOT8(a11, w1, sB0, sB1);
            DOT8(a20, w2, hA0, hA1); DOT8(a21, w2, hB0, hB1);
        }
        // combine row-halves (adjacent lanes), store complete dots + bias
        a00 += __shfl_xor(a00, 1); a01 += __shfl_xor(a01, 1);
        a10 += __shfl_xor(a10, 1); a11 += __shfl_xor(a11, 1);
        a20 += __shfl_xor(a20, 1); a21 += __shfl_xor(a21, 1);
        if (half == 0) {
            lds[OFF_XMRM + c0]                    = a00 + b0;
            lds[OFF_XMRM + 384 + c0]              = a01 + b0;
            lds[OFF_XMRM + m1 * 768 + c1]         = a10 + b1;
            lds[OFF_XMRM + m1 * 768 + 384 + c1]   = a11 + b1;
            lds[OFF_XMRM + 768 + 128 + c0]        = a20 + b2;
            lds[OFF_XMRM + 768 + 384 + 128 + c0]  = a21 + b2;
        }
        __syncthreads();

        // ---- E: gates + h update (R5-validated)
        if (tid < 256) {
            const int eseq = tid >> 7, ehh = tid & 127;
            const float* xm = lds + OFF_XMRM + eseq * 384;
            const float* rm = lds + OFF_XMRM + 768 + eseq * 384;
            float xz = xm[ehh], xr = xm[128 + ehh], xh_ = xm[256 + ehh];
            float rz = rm[ehh], rr = rm[128 + ehh], rh = rm[256 + ehh];
            float z = __fdividef(1.0f, 1.0f + __expf(-(xz + rz)));
            float r = __fdividef(1.0f, 1.0f + __expf(-(xr + rr)));
            float hc = xh_ + r * rh;
            hc = hc > 0.0f ? hc : 0.0f;
            float hold = lds[OFF_HST + eseq * 128 + ehh];
            lds[OFF_HST + eseq * 128 + ehh] = z * hold + (1.0f - z) * hc;
        }
        __syncthreads();
    }

    if (tid < 256) {
        const int eseq = tid >> 7, ehh = tid & 127;
        out[(size_t)(bn0 + eseq) * 128 + ehh] = lds[OFF_HST + eseq * 128 + ehh];
    }
}

extern "C" void kernel_launch(void* const* d_in, const int* in_sizes, int n_in,
                              void* d_out, int out_size, void* d_ws, size_t ws_size,
                              hipStream_t stream) {
    (void)in_sizes; (void)n_in; (void)out_size; (void)d_ws; (void)ws_size;
    const float* x      = (const float*)d_in[0];
    const float* att_v  = (const float*)d_in[1];
    const float* att_w  = (const float*)d_in[2];
    const float* att_u  = (const float*)d_in[3];
    const float* gk     = (const float*)d_in[4];
    const float* grk    = (const float*)d_in[5];
    const float* gbias  = (const float*)d_in[6];
    float* out = (float*)d_out;
    hipLaunchKernelGGL(attn_gru_kernel, dim3(256), dim3(512), 0, stream,
                       x, att_v, att_w, att_u, gk, grk, gbias, out);
}

// Round 16
// 641.273 us; speedup vs baseline: 1.4189x; 1.4189x over previous
//
#include <hip/hip_runtime.h>

// AttentionRNN: B=64, NUM=8, TC=64, H=128. bn=512 sequences.
// R16: wave-specialized overlap. 256 thr/block, 2 seqs, 256 blocks, 1 block/CU
// (105KB LDS). Per step: P1 = [waves 0-1: rm = h@grk, float3 col-stream] ||
// [wave 2: seq0 A+C+softmax in-wave; wave 3: seq1] -> barrier ->
// P2 = waves 0-1: xm = x_t@gk -> barrier -> E (all) -> barrier. 3 barriers/step.
// uproj in LDS transposed [seq][s][hh] (lane-consecutive). att_w transposed
// with stride-129 pad (conflict-free). Simple load-then-FMA chunks (R9 rule).

#define OFF_UPT   0        // [2][64][128] uproj^T
#define OFF_ATWT  16384    // [64][129] att_w^T padded; U staged here in prologue
#define OFF_XMRM  24640    // [mat2][seq2][384]
#define OFF_HST   26176    // [2][128]
#define OFF_HPART 26432    // [2][64]
#define OFF_XTV   26560    // [2][128]
#define OFF_VV    26816    // [64]
#define LDS_FLOATS 26880   // 105 KB -> 1 block/CU

#define ROW3(WW, S0, S1) do { \
    a0x += (WW).x*(S0); a0y += (WW).y*(S0); a0z += (WW).z*(S0); \
    a1x += (WW).x*(S1); a1y += (WW).y*(S1); a1z += (WW).z*(S1); } while(0)

// complete 128-row x 3-col matvec for both seqs; weights streamed from L2 in
// 8 simple chunks (16 rows, float3/lane = contiguous 768B/instr per wave)
#define GEMV3(WP, IOFF, OBASE, B0, B1, B2) do { \
    float a0x=(B0), a0y=(B1), a0z=(B2); \
    float a1x=(B0), a1y=(B1), a1z=(B2); \
    _Pragma("unroll 1") \
    for (int c_ = 0; c_ < 8; ++c_) { \
        float3 w_[16]; \
        _Pragma("unroll") \
        for (int r_ = 0; r_ < 16; ++r_) \
            w_[r_] = *(const float3*)((WP) + (size_t)(c_*16 + r_)*384); \
        const float* ib_ = lds + (IOFF) + c_*16; \
        _Pragma("unroll") \
        for (int q_ = 0; q_ < 4; ++q_) { \
            float4 i0_ = *(const float4*)(ib_ + q_*4); \
            float4 i1_ = *(const float4*)(ib_ + 128 + q_*4); \
            ROW3(w_[q_*4+0], i0_.x, i1_.x); \
            ROW3(w_[q_*4+1], i0_.y, i1_.y); \
            ROW3(w_[q_*4+2], i0_.z, i1_.z); \
            ROW3(w_[q_*4+3], i0_.w, i1_.w); \
        } \
    } \
    lds[(OBASE) + col0]           = a0x; \
    lds[(OBASE) + col0 + 1]       = a0y; \
    lds[(OBASE) + col0 + 2]       = a0z; \
    lds[(OBASE) + 384 + col0]     = a1x; \
    lds[(OBASE) + 384 + col0 + 1] = a1y; \
    lds[(OBASE) + 384 + col0 + 2] = a1z; \
} while(0)

__global__ __launch_bounds__(256, 1)
void attn_gru_kernel(const float* __restrict__ x, const float* __restrict__ att_v,
                     const float* __restrict__ att_w, const float* __restrict__ att_u,
                     const float* __restrict__ gk, const float* __restrict__ grk,
                     const float* __restrict__ gbias, float* __restrict__ out) {
    __shared__ float lds[LDS_FLOATS];
    const int tid = threadIdx.x;
    const int bn0 = blockIdx.x * 2;

    // ---- prologue 1: stage U (in ATWT area), v; zero h
    for (int i = tid; i < 4096; i += 256) lds[OFF_ATWT + i] = att_u[i];
    if (tid < 64) lds[OFF_VV + tid] = att_v[tid];
    lds[OFF_HST + tid] = 0.0f;
    __syncthreads();

    // ---- prologue 2: uproj in regs (R9-validated), then write transposed
    {
        const int pseq = tid >> 7, phh = tid & 127;
        float upreg[64];
        #pragma unroll
        for (int s2 = 0; s2 < 64; ++s2) upreg[s2] = 0.0f;
        const float* xb = x + (size_t)(bn0 + pseq) * 8192 + phh;
        for (int tt = 0; tt < 64; ++tt) {
            float xv = xb[tt * 128];
            const float* Ur = lds + OFF_ATWT + tt * 64;
            #pragma unroll
            for (int s2 = 0; s2 < 64; ++s2) upreg[s2] += xv * Ur[s2];
        }
        __syncthreads();   // all U reads done before ATWT overwrite
        #pragma unroll
        for (int s2 = 0; s2 < 64; ++s2)
            lds[OFF_UPT + (pseq * 64 + s2) * 128 + phh] = upreg[s2];
    }
    // stage att_w^T with stride-129 pad (overwrites U region)
    for (int i = tid; i < 8192; i += 256) {
        int k = i >> 6, s = i & 63;
        lds[OFF_ATWT + s * 129 + k] = att_w[i];
    }
    __syncthreads();

    // ---- role constants
    const int wv = tid >> 6, lane = tid & 63;
    const int col0 = 3 * tid;                    // valid for tid<128
    const float* gkp = gk + (tid < 128 ? col0 : 0);
    const float* grp = grk + (tid < 128 ? col0 : 0);
    float bi0 = 0.f, bi1 = 0.f, bi2 = 0.f, br0 = 0.f, br1 = 0.f, br2 = 0.f;
    if (tid < 128) {
        bi0 = gbias[col0];       bi1 = gbias[col0 + 1];       bi2 = gbias[col0 + 2];
        br0 = gbias[384 + col0]; br1 = gbias[384 + col0 + 1]; br2 = gbias[384 + col0 + 2];
    }
    float sv = 0.0f;
    #pragma unroll
    for (int k = 0; k < 64; ++k) sv += lds[OFF_VV + k];
    const int aseq = (wv >= 2) ? (wv - 2) : 0;
    const float* xq = x + (size_t)(bn0 + aseq) * 8192 + lane;

    #pragma unroll 1
    for (int t = 0; t < 64; ++t) {
        if (wv < 2) {
            // ---- P1 (waves 0-1): rm = h @ grk, complete dots + bias
            GEMV3(grp, OFF_HST, OFF_XMRM + 768, br0, br1, br2);
        } else {
            // ---- P1 (waves 2-3): attention for seq = wv-2, fully in-wave
            // A: h_part[s=lane] = sum_k W[k][lane] * h[k]
            float pa = 0.0f;
            {
                const float* at = lds + OFF_ATWT + lane * 129;  // bank-spread
                const float* hs = lds + OFF_HST + aseq * 128;   // broadcast
                #pragma unroll 8
                for (int k = 0; k < 128; ++k) pa += at[k] * hs[k];
            }
            lds[OFF_HPART + aseq * 64 + lane] = pa;
            // same-wave DS ordering: write lands before reads below
            float xv0 = xq[t * 128];
            float xv1 = xq[t * 128 + 64];
            float den0 = 0.0f, den1 = 0.0f;
            {
                const float* upb = lds + OFF_UPT + aseq * 64 * 128 + lane;
                const float* hpb = lds + OFF_HPART + aseq * 64;
                #pragma unroll 8
                for (int s2 = 0; s2 < 64; ++s2) {
                    float hp = hpb[s2];                 // broadcast
                    float v  = lds[OFF_VV + s2];        // broadcast
                    float u0 = upb[s2 * 128];           // lane-consecutive
                    float u1 = upb[s2 * 128 + 64];
                    den0 += v * __fdividef(1.0f, __expf(2.0f * (hp + u0)) + 1.0f);
                    den1 += v * __fdividef(1.0f, __expf(2.0f * (hp + u1)) + 1.0f);
                }
            }
            float p0 = __expf(sv - 2.0f * den0);   // |e| <= sum|v| ~ 5: safe
            float p1 = __expf(sv - 2.0f * den1);
            float ws = p0 + p1;
            #pragma unroll
            for (int off = 1; off <= 32; off <<= 1) ws += __shfl_xor(ws, off, 64);
            float inv = __fdividef(1.0f, ws);
            lds[OFF_XTV + aseq * 128 + lane]      = p0 * inv * xv0;
            lds[OFF_XTV + aseq * 128 + 64 + lane] = p1 * inv * xv1;
        }
        __syncthreads();

        // ---- P2 (waves 0-1): xm = x_t @ gk, complete dots + bias
        if (wv < 2) {
            GEMV3(gkp, OFF_XTV, OFF_XMRM, bi0, bi1, bi2);
        }
        __syncthreads();

        // ---- E: gates + h update (all 256 threads)
        {
            const int eseq = tid >> 7, ehh = tid & 127;
            const float* xm = lds + OFF_XMRM + eseq * 384;
            const float* rm = lds + OFF_XMRM + 768 + eseq * 384;
            float xz = xm[ehh], xr = xm[128 + ehh], xh_ = xm[256 + ehh];
            float rz = rm[ehh], rr = rm[128 + ehh], rh = rm[256 + ehh];
            float z = __fdividef(1.0f, 1.0f + __expf(-(xz + rz)));
            float r = __fdividef(1.0f, 1.0f + __expf(-(xr + rr)));
            float hc = xh_ + r * rh;
            hc = hc > 0.0f ? hc : 0.0f;
            float hold = lds[OFF_HST + eseq * 128 + ehh];
            lds[OFF_HST + eseq * 128 + ehh] = z * hold + (1.0f - z) * hc;
        }
        __syncthreads();
    }

    {
        const int eseq = tid >> 7, ehh = tid & 127;
        out[(size_t)(bn0 + eseq) * 128 + ehh] = lds[OFF_HST + eseq * 128 + ehh];
    }
}

extern "C" void kernel_launch(void* const* d_in, const int* in_sizes, int n_in,
                              void* d_out, int out_size, void* d_ws, size_t ws_size,
                              hipStream_t stream) {
    (void)in_sizes; (void)n_in; (void)out_size; (void)d_ws; (void)ws_size;
    const float* x      = (const float*)d_in[0];
    const float* att_v  = (const float*)d_in[1];
    const float* att_w  = (const float*)d_in[2];
    const float* att_u  = (const float*)d_in[3];
    const float* gk     = (const float*)d_in[4];
    const float* grk    = (const float*)d_in[5];
    const float* gbias  = (const float*)d_in[6];
    float* out = (float*)d_out;
    hipLaunchKernelGGL(attn_gru_kernel, dim3(256), dim3(256), 0, stream,
                       x, att_v, att_w, att_u, gk, grk, gbias, out);
}

// Round 17
// 518.722 us; speedup vs baseline: 1.7541x; 1.2363x over previous
//
#include <hip/hip_runtime.h>

// AttentionRNN: B=64, NUM=8, TC=64, H=128. bn=512 sequences.
// R17 = R14's LDS-resident byte-cut with R9's clean schedule:
//  - rows 0..47 of gk+grk resident in LDS (144KB, staged once, float4 copies)
//  - D: prefetch rows 48..63 -> resident-FMA block (hides latency) ->
//    FMA prefetched chunk -> R9's simple load-then-FMA for rows 64..127.
//    NO slicing/interleave (R14 lesson), NO manual dbuf (R11 lesson).
//  - A/B: R9 wreg form. C/softmax: R12 max-free. E: R12. All validated.
// 256 thr/block, launch_bounds(256,1), 256 blocks, 2 seqs/block, 1 block/CU.

#define OFF_WL    0        // [2][48][384] resident rows; U staged here in prologue
#define OFF_XMRM  36864    // [mat][seq][384]
#define OFF_HST   38400    // [2][128]
#define OFF_HPP   38656    // [2][4][64]
#define OFF_HPART 39168    // [2][64]
#define OFF_XTV   39296    // [2][128]
#define OFF_VV    39552    // [64]
#define OFF_RED   39616    // [16]
#define LDS_FLOATS 39632   // ~154.8 KB

#define FMA4(ACC, W, S) do { (ACC).x += (W).x*(S); (ACC).y += (W).y*(S); \
                             (ACC).z += (W).z*(S); (ACC).w += (W).w*(S); } while(0)

// load 16 float4 weight rows RB..RB+15 from global
#define LOADW(BUF, RB) do { \
    _Pragma("unroll") \
    for (int r_ = 0; r_ < 16; ++r_) \
        BUF[r_] = *(const float4*)(Wm + (size_t)((RB) + r_) * 384); \
} while (0)

// FMA 16-row chunk BUF (rows RB..RB+15) against both seqs' inputs
#define FMACH(BUF, RB) do { \
    const float* i0_ = lds + ivoff + (RB); \
    float4 iA0 = *(const float4*)(i0_); \
    float4 iA1 = *(const float4*)(i0_ + 4); \
    float4 iA2 = *(const float4*)(i0_ + 8); \
    float4 iA3 = *(const float4*)(i0_ + 12); \
    float4 iB0 = *(const float4*)(i0_ + 128); \
    float4 iB1 = *(const float4*)(i0_ + 132); \
    float4 iB2 = *(const float4*)(i0_ + 136); \
    float4 iB3 = *(const float4*)(i0_ + 140); \
    FMA4(a0, BUF[0],  iA0.x); FMA4(a1, BUF[0],  iB0.x); \
    FMA4(a0, BUF[1],  iA0.y); FMA4(a1, BUF[1],  iB0.y); \
    FMA4(a0, BUF[2],  iA0.z); FMA4(a1, BUF[2],  iB0.z); \
    FMA4(a0, BUF[3],  iA0.w); FMA4(a1, BUF[3],  iB0.w); \
    FMA4(a0, BUF[4],  iA1.x); FMA4(a1, BUF[4],  iB1.x); \
    FMA4(a0, BUF[5],  iA1.y); FMA4(a1, BUF[5],  iB1.y); \
    FMA4(a0, BUF[6],  iA1.z); FMA4(a1, BUF[6],  iB1.z); \
    FMA4(a0, BUF[7],  iA1.w); FMA4(a1, BUF[7],  iB1.w); \
    FMA4(a0, BUF[8],  iA2.x); FMA4(a1, BUF[8],  iB2.x); \
    FMA4(a0, BUF[9],  iA2.y); FMA4(a1, BUF[9],  iB2.y); \
    FMA4(a0, BUF[10], iA2.z); FMA4(a1, BUF[10], iB2.z); \
    FMA4(a0, BUF[11], iA2.w); FMA4(a1, BUF[11], iB2.w); \
    FMA4(a0, BUF[12], iA3.x); FMA4(a1, BUF[12], iB3.x); \
    FMA4(a0, BUF[13], iA3.y); FMA4(a1, BUF[13], iB3.y); \
    FMA4(a0, BUF[14], iA3.z); FMA4(a1, BUF[14], iB3.z); \
    FMA4(a0, BUF[15], iA3.w); FMA4(a1, BUF[15], iB3.w); \
} while (0)

__global__ __launch_bounds__(256, 1)
void attn_gru_kernel(const float* __restrict__ x, const float* __restrict__ att_v,
                     const float* __restrict__ att_w, const float* __restrict__ att_u,
                     const float* __restrict__ gk, const float* __restrict__ grk,
                     const float* __restrict__ gbias, float* __restrict__ out) {
    __shared__ float lds[LDS_FLOATS];
    const int tid = threadIdx.x;
    const int bn0 = blockIdx.x * 2;

    // ---- prologue 1: U (aliased into WL region), v, h=0
    for (int i = tid; i < 4096; i += 256) lds[OFF_WL + i] = att_u[i];
    if (tid < 64) lds[OFF_VV + tid] = att_v[tid];
    lds[OFF_HST + tid] = 0.0f;
    __syncthreads();

    const int seq = tid >> 7;   // 0/1
    const int hh  = tid & 127;
    const int s_  = tid & 63;
    const int hg  = tid >> 6;   // wave id

    // uproj[seq][hh][0..63] in registers (R9-validated)
    float upreg[64];
    #pragma unroll
    for (int s2 = 0; s2 < 64; ++s2) upreg[s2] = 0.0f;
    {
        const float* xb = x + (size_t)(bn0 + seq) * 8192 + hh;
        for (int t = 0; t < 64; ++t) {
            float xv = xb[t * 128];
            const float* Ur = lds + OFF_WL + t * 64;
            #pragma unroll
            for (int s2 = 0; s2 < 64; ++s2) upreg[s2] += xv * Ur[s2];
        }
    }
    // att_w fragment in registers (R9-validated A)
    float wreg[32];
    #pragma unroll
    for (int k = 0; k < 32; ++k) wreg[k] = att_w[(hg * 32 + k) * 64 + s_];

    __syncthreads();   // U reads done -> safe to overwrite WL region

    // ---- prologue 2: resident rows 0..47 of both matrices (contiguous float4)
    {
        const float4* g4 = (const float4*)gk;
        const float4* r4 = (const float4*)grk;
        float4* wl = (float4*)(lds + OFF_WL);
        #pragma unroll 4
        for (int i = tid; i < 4608; i += 256) wl[i] = g4[i];          // 18432 floats
        #pragma unroll 4
        for (int i = tid; i < 4608; i += 256) wl[4608 + i] = r4[i];
    }

    // phase-D per-thread constants (R12/R14-validated mapping)
    const int col4 = tid * 4;                 // 0..764 for tid<192
    const int dmat = (col4 >= 384) ? 1 : 0;
    const int dj   = col4 - dmat * 384;
    const float* Wm = (dmat ? grk : gk) + dj;
    const int ivoff  = dmat ? OFF_HST : OFF_XTV;
    const int wlbase = OFF_WL + dmat * 18432 + dj;
    float4 dbias = make_float4(0.f, 0.f, 0.f, 0.f);
    if (tid < 192) dbias = *(const float4*)(gbias + dmat * 384 + dj);

    const float* xcol = x + (size_t)(bn0 + seq) * 8192 + hh;

    __syncthreads();

    for (int t = 0; t < 64; ++t) {
        float xv = xcol[t * 128];   // prefetch (L3-hot), used after softmax

        // ---- A: h_part partials (R9-validated)
        {
            float p0 = 0.f, p1 = 0.f;
            #pragma unroll
            for (int k = 0; k < 32; ++k) {
                float w = wreg[k];
                p0 += lds[OFF_HST + hg * 32 + k] * w;
                p1 += lds[OFF_HST + 128 + hg * 32 + k] * w;
            }
            lds[OFF_HPP + (0 * 4 + hg) * 64 + s_] = p0;
            lds[OFF_HPP + (1 * 4 + hg) * 64 + s_] = p1;
        }
        __syncthreads();

        // ---- B: reduce 4 row-group partials (R9-validated)
        if (tid < 128) {
            int sq = tid >> 6, ss = tid & 63;
            lds[OFF_HPART + sq * 64 + ss] =
                  lds[OFF_HPP + (sq * 4 + 0) * 64 + ss]
                + lds[OFF_HPP + (sq * 4 + 1) * 64 + ss]
                + lds[OFF_HPP + (sq * 4 + 2) * 64 + ss]
                + lds[OFF_HPP + (sq * 4 + 3) * 64 + ss];
        }
        __syncthreads();

        // ---- C: e = sum_s tanh(hp+up)*v; max-free softmax (R12-validated)
        float e = 0.f;
        {
            const float* hp = lds + OFF_HPART + seq * 64;
            #pragma unroll
            for (int s2 = 0; s2 < 64; ++s2) {
                float arg = hp[s2] + upreg[s2];
                float u2 = __expf(2.0f * arg);
                float th = 1.0f - __fdividef(2.0f, u2 + 1.0f);
                e += th * lds[OFF_VV + s2];
            }
        }
        float p = __expf(e);                 // |e| <= sum|v| ~ 5: fp32-safe
        float sm = p;
        #pragma unroll
        for (int off = 32; off >= 1; off >>= 1) sm += __shfl_xor(sm, off, 64);
        if ((tid & 63) == 0) lds[OFF_RED + 8 + hg] = sm;
        __syncthreads();
        float denom = lds[OFF_RED + 8 + seq * 2] + lds[OFF_RED + 8 + seq * 2 + 1];
        float a = __fdividef(p, denom);
        lds[OFF_XTV + seq * 128 + hh] = a * xv;
        __syncthreads();

        // ---- D: prefetch rows 48..63 -> resident rows 0..47 (LDS) ->
        //         prefetched chunk -> streamed rows 64..127 (R9 pattern)
        if (tid < 192) {
            float4 a0 = make_float4(0.f, 0.f, 0.f, 0.f);
            float4 a1 = make_float4(0.f, 0.f, 0.f, 0.f);
            float4 w0[16];
            LOADW(w0, 48);                       // in flight across resident block
            #pragma unroll
            for (int r = 0; r < 48; ++r) {       // resident: LDS pipe, no L2
                float4 wr = *(const float4*)(lds + wlbase + r * 384);
                float i0 = lds[ivoff + r];
                float i1 = lds[ivoff + 128 + r];
                FMA4(a0, wr, i0);
                FMA4(a1, wr, i1);
            }
            FMACH(w0, 48);                       // landed during resident block
            #pragma unroll 1
            for (int c = 0; c < 4; ++c) {        // rows 64..127, simple pattern
                float4 w[16];
                LOADW(w, 64 + c * 16);
                FMACH(w, 64 + c * 16);
            }
            *(float4*)(lds + OFF_XMRM + (dmat * 2 + 0) * 384 + dj) =
                make_float4(a0.x + dbias.x, a0.y + dbias.y, a0.z + dbias.z, a0.w + dbias.w);
            *(float4*)(lds + OFF_XMRM + (dmat * 2 + 1) * 384 + dj) =
                make_float4(a1.x + dbias.x, a1.y + dbias.y, a1.z + dbias.z, a1.w + dbias.w);
        }
        __syncthreads();

        // ---- E: gates (R12-validated)
        {
            const float* xm = lds + OFF_XMRM + (0 * 2 + seq) * 384;
            const float* rm = lds + OFF_XMRM + (1 * 2 + seq) * 384;
            float xz = xm[hh], xr = xm[128 + hh], xh = xm[256 + hh];
            float rz = rm[hh], rr = rm[128 + hh], rh = rm[256 + hh];
            float z = __fdividef(1.0f, 1.0f + __expf(-(xz + rz)));
            float r = __fdividef(1.0f, 1.0f + __expf(-(xr + rr)));
            float hc = xh + r * rh;
            hc = hc > 0.f ? hc : 0.f;
            float hold = lds[OFF_HST + seq * 128 + hh];
            lds[OFF_HST + seq * 128 + hh] = z * hold + (1.0f - z) * hc;
        }
        __syncthreads();
    }

    out[(size_t)(bn0 + seq) * 128 + hh] = lds[OFF_HST + seq * 128 + hh];
}

extern "C" void kernel_launch(void* const* d_in, const int* in_sizes, int n_in,
                              void* d_out, int out_size, void* d_ws, size_t ws_size,
                              hipStream_t stream) {
    (void)in_sizes; (void)n_in; (void)out_size; (void)d_ws; (void)ws_size;
    const float* x      = (const float*)d_in[0];
    const float* att_v  = (const float*)d_in[1];
    const float* att_w  = (const float*)d_in[2];
    const float* att_u  = (const float*)d_in[3];
    const float* gk     = (const float*)d_in[4];
    const float* grk    = (const float*)d_in[5];
    const float* gbias  = (const float*)d_in[6];
    float* out = (float*)d_out;
    hipLaunchKernelGGL(attn_gru_kernel, dim3(256), dim3(256), 0, stream,
                       x, att_v, att_w, att_u, gk, grk, gbias, out);
}